// Round 6
// baseline (216.677 us; speedup 1.0000x reference)
//
#include <hip/hip_runtime.h>
#include <stdint.h>

#define NROWS 16384   // 16*32*32 spatial positions
#define NCODES 8192
#define DIM 256
// score = 1024 + dot - ||e||^2/2  (higher = closer). bf16 dist-error sigma
// ~0.05 in score units. EPS_S = 0.4 (8 sigma one-sided); SM = 0.8 (needs
// > 2*EPS + pack slack 0.008). Validated absmax=0 in R4/R5.
#define EPS_S 0.4f
#define SM 0.8f

typedef __attribute__((ext_vector_type(8))) short bf16x8;  // 8 bf16 = 4 VGPRs
typedef __attribute__((ext_vector_type(4))) float f32x4;
typedef unsigned int uint32;

__device__ __forceinline__ unsigned short f2bf(float f) {
  union { float f; unsigned int u; } v; v.f = f;
  unsigned int u = v.u;
  return (unsigned short)((u + 0x7FFFu + ((u >> 16) & 1u)) >> 16);  // RNE
}

__device__ __forceinline__ void glds16(const void* g, void* l) {
  __builtin_amdgcn_global_load_lds(
      (const __attribute__((address_space(1))) unsigned int*)g,
      (__attribute__((address_space(3))) unsigned int*)l, 16, 0, 0);
}

// exact-path u64 key = order-preserving dist bits << 32 | idx (min = best+lowest idx)
__device__ __forceinline__ unsigned long long packdi(float d, int idx) {
  unsigned int u = __float_as_uint(d);
  u = (u & 0x80000000u) ? ~u : (u | 0x80000000u);
  return ((unsigned long long)u << 32) | (unsigned int)idx;
}
__device__ __forceinline__ unsigned long long u64min(unsigned long long a,
                                                     unsigned long long b) {
  return a < b ? a : b;
}
__device__ __forceinline__ unsigned long long shflx64(unsigned long long v, int m) {
  int lo = __shfl_xor((int)(unsigned int)v, m);
  int hi = __shfl_xor((int)(v >> 32), m);
  return ((unsigned long long)(unsigned int)hi << 32) | (unsigned int)lo;
}
__device__ __forceinline__ uint32 umax(uint32 a, uint32 b) { return a > b ? a : b; }
__device__ __forceinline__ uint32 umin(uint32 a, uint32 b) { return a < b ? a : b; }

// ---- Phase 0 (fused): z transpose+bf16, codebook bf16+norms ----------------
__global__ __launch_bounds__(256) void prep(const float* __restrict__ z,
                                            const float* __restrict__ cb,
                                            float* __restrict__ flatz,
                                            ushort* __restrict__ zb,
                                            ushort* __restrict__ eb,
                                            float* __restrict__ enorm) {
  __shared__ float t[32][33];
  const int blk = blockIdx.x;
  if (blk < 4096) {  // prep_z part: NCHW -> (row, d), fp32 copy into zq
    const int tx = threadIdx.x & 31, ty = threadIdx.x >> 5;  // 32 x 8
    const int ht = blk & 31, ct = (blk >> 5) & 7, b = blk >> 8;
    const float* src = z + (size_t)b * 262144 + (size_t)(ct * 32) * 1024 + ht * 32;
#pragma unroll
    for (int i = 0; i < 4; ++i) {
      int c = ty + i * 8;
      t[c][tx] = src[c * 1024 + tx];
    }
    __syncthreads();
#pragma unroll
    for (int i = 0; i < 4; ++i) {
      int hw = ty + i * 8;
      int row = b * 1024 + ht * 32 + hw;
      float v = t[tx][hw];
      flatz[(size_t)row * 256 + ct * 32 + tx] = v;
      zb[(size_t)row * 256 + ct * 32 + tx] = f2bf(v);
    }
  } else {  // prep_cb part
    const int lane = threadIdx.x & 63, wave = threadIdx.x >> 6;
    const int code = (blk - 4096) * 4 + wave;
    float4 v = *(const float4*)(cb + (size_t)code * 256 + lane * 4);
    ushort4 o;
    o.x = f2bf(v.x); o.y = f2bf(v.y); o.z = f2bf(v.z); o.w = f2bf(v.w);
    *(ushort4*)(eb + (size_t)code * 256 + lane * 4) = o;
    float ss = v.x * v.x + v.y * v.y + v.z * v.z + v.w * v.w;
#pragma unroll
    for (int s = 1; s < 64; s <<= 1) ss += __shfl_xor(ss, s);
    if (lane == 0) enorm[code] = ss;
  }
}

// ---- Phase 1: bf16 MFMA score GEMM, 128 codes x 256 zrows, A+B LDS dbuf ----
// 4 waves = (wr: code half) x (wc: zrow half): 64 codes x 128 zrows each,
// 4i x 8j frags of 16x16x32 -> 32 MFMA per barrier (2x R5's ratio).
// Conflict-free swizzle validated R5 (SQ_LDS_BANK_CONFLICT = 0).
// Epilogue: per 32-code chunk store u32: score&~63 | gapflag<<5 | id(5b).
__global__ __launch_bounds__(256, 2) void vq_gemm(const ushort* __restrict__ eb,
                                                  const ushort* __restrict__ zb,
                                                  const float* __restrict__ enorm,
                                                  uint32* __restrict__ bm) {
  __shared__ __align__(16) ushort As[2][4096];  // 2 x (128 codes x 32 k) = 16 KB
  __shared__ __align__(16) ushort Bs[2][8192];  // 2 x (256 zrows x 32 k) = 32 KB
  const int tid = threadIdx.x;
  const int wave = tid >> 6, lane = tid & 63;
  const int wr = wave >> 1, wc = wave & 1;  // code half / zrow half
  const int code0 = blockIdx.x * 128;
  const int zrow0 = blockIdx.y * 256;
  const int q = lane >> 4, l15 = lane & 15;
  const int slot = (q ^ ((l15 >> 1) & 3)) * 8;  // conflict-free un-swizzle

  // acc init: 1024 - 0.5*||e||^2 (score trick) replicated across 8 j-frags
  f32x4 acc[4][8];
#pragma unroll
  for (int i = 0; i < 4; ++i) {
    float4 e = *(const float4*)(enorm + code0 + wr * 64 + i * 16 + q * 4);
    f32x4 c0 = {1024.f - 0.5f * e.x, 1024.f - 0.5f * e.y,
                1024.f - 0.5f * e.z, 1024.f - 0.5f * e.w};
#pragma unroll
    for (int j = 0; j < 8; ++j) acc[i][j] = c0;
  }

  // staging: lane l writes 16B to LDS slot l&3 of row l>>2 (glds constraint);
  // global k-chunk = (l&3) ^ ((l>>3)&3)
  const int r_in = lane >> 2;
  const int kc = (lane & 3) ^ ((lane >> 3) & 3);
  const ushort* aG0 = eb + (size_t)(code0 + wave * 16 + r_in) * 256 + kc * 8;
  const ushort* aG1 = eb + (size_t)(code0 + 64 + wave * 16 + r_in) * 256 + kc * 8;
  const ushort* bG[4];
#pragma unroll
  for (int g = 0; g < 4; ++g)
    bG[g] = zb + (size_t)(zrow0 + wave * 64 + g * 16 + r_in) * 256 + kc * 8;

  glds16(aG0, &As[0][wave * 512]);
  glds16(aG1, &As[0][(wave + 4) * 512]);
#pragma unroll
  for (int g = 0; g < 4; ++g) glds16(bG[g], &Bs[0][(wave * 4 + g) * 512]);

#pragma unroll
  for (int k0 = 0; k0 < 8; ++k0) {
    const int cur = k0 & 1;
    __syncthreads();  // drains glds of stage k0; protects buf cur^1 reads
    if (k0 < 7) {
      glds16(aG0 + (k0 + 1) * 32, &As[cur ^ 1][wave * 512]);
      glds16(aG1 + (k0 + 1) * 32, &As[cur ^ 1][(wave + 4) * 512]);
#pragma unroll
      for (int g = 0; g < 4; ++g)
        glds16(bG[g] + (k0 + 1) * 32, &Bs[cur ^ 1][(wave * 4 + g) * 512]);
    }
    bf16x8 af[4], bf[8];
#pragma unroll
    for (int i = 0; i < 4; ++i)
      af[i] = *(const bf16x8*)(&As[cur][(wr * 64 + i * 16 + l15) * 32 + slot]);
#pragma unroll
    for (int j = 0; j < 8; ++j)
      bf[j] = *(const bf16x8*)(&Bs[cur][(wc * 128 + j * 16 + l15) * 32 + slot]);
#pragma unroll
    for (int i = 0; i < 4; ++i)
#pragma unroll
      for (int j = 0; j < 8; ++j)
        acc[i][j] = __builtin_amdgcn_mfma_f32_16x16x32_bf16(af[i], bf[j],
                                                            acc[i][j], 0, 0, 0);
  }

  // epilogue: C/D col=lane&15 (zrow), row=q*4+r (code in 16-frag). Per i-frag
  // top-2 (id = (i&1)<<4 | q*4+r), then merge frag pairs -> 32-code chunks.
  const int cid0 = blockIdx.x * 4 + wr * 2;  // chunk32 id base
#pragma unroll
  for (int j = 0; j < 8; ++j) {
    uint32 t1[4], t2[4];
#pragma unroll
    for (int i = 0; i < 4; ++i) {
      uint32 base = ((uint32)(i & 1) << 4) | (uint32)(q * 4);
      uint32 pv0 = (__float_as_uint(acc[i][j][0]) & ~63u) | base;
      uint32 pv1 = (__float_as_uint(acc[i][j][1]) & ~63u) | (base + 1u);
      uint32 pv2 = (__float_as_uint(acc[i][j][2]) & ~63u) | (base + 2u);
      uint32 pv3 = (__float_as_uint(acc[i][j][3]) & ~63u) | (base + 3u);
      uint32 x01 = umax(pv0, pv1), n01 = umin(pv0, pv1);
      uint32 x23 = umax(pv2, pv3), n23 = umin(pv2, pv3);
      uint32 m1 = umax(x01, x23);
      uint32 m2 = umax(umin(x01, x23), umax(n01, n23));
#pragma unroll
      for (int m = 16; m < 64; m <<= 1) {  // merge the 4 q-groups
        uint32 o1 = (uint32)__shfl_xor((int)m1, m);
        uint32 o2 = (uint32)__shfl_xor((int)m2, m);
        m2 = umax(umax(m2, o2), umin(m1, o1));
        m1 = umax(m1, o1);
      }
      t1[i] = m1; t2[i] = m2;
    }
    uint32 r01, r23;
    {
      uint32 m1 = umax(t1[0], t1[1]);
      uint32 m2 = umax(umin(t1[0], t1[1]), umax(t2[0], t2[1]));
      float s1 = __uint_as_float(m1 & ~63u), s2 = __uint_as_float(m2 & ~63u);
      r01 = (s1 - s2 > SM) ? (m1 | 32u) : m1;
    }
    {
      uint32 m1 = umax(t1[2], t1[3]);
      uint32 m2 = umax(umin(t1[2], t1[3]), umax(t2[2], t2[3]));
      float s1 = __uint_as_float(m1 & ~63u), s2 = __uint_as_float(m2 & ~63u);
      r23 = (s1 - s2 > SM) ? (m1 | 32u) : m1;
    }
    if (lane < 16) {
      int zr = zrow0 + wc * 128 + j * 16 + l15;
      uint2 o; o.x = r01; o.y = r23;
      *(uint2*)(bm + (size_t)zr * 256 + cid0) = o;
    }
  }
}

// exact fp32 distances for one 16-code chunk; summation order / lane split /
// tie-break bit-identical to the R2..R5-validated slow path.
__device__ __forceinline__ unsigned long long chunk_exact(
    int chunk, const float* __restrict__ zrow, const float* __restrict__ cb,
    const float* __restrict__ enorm, int lane) {
  const int code = chunk * 16 + (lane >> 2);
  const float* zp = zrow + (lane & 3) * 64;
  const float* cp = cb + (size_t)code * 256 + (lane & 3) * 64;
  float s = 0.f;
#pragma unroll
  for (int d = 0; d < 64; d += 4) {
    float4 zv = *(const float4*)(zp + d);
    float4 cv = *(const float4*)(cp + d);
    s = fmaf(zv.x, cv.x, s); s = fmaf(zv.y, cv.y, s);
    s = fmaf(zv.z, cv.z, s); s = fmaf(zv.w, cv.w, s);
  }
  s += __shfl_xor(s, 1);
  s += __shfl_xor(s, 2);
  float dist = fmaf(-2.f, s, enorm[code]);
  unsigned long long key = ((lane & 3) == 0) ? packdi(dist, code) : ~0ull;
#pragma unroll
  for (int m = 1; m < 64; m <<= 1) key = u64min(key, shflx64(key, m));
  return key;  // wave-uniform
}

// ---- Phase 2: one wave per row over 256 chunk32 maxima ---------------------
// Fast path (winner flag AND global margin > SM): proven exact, no recompute.
// Slow path: exact fp32 winner chunk32 (two chunk16 calls), then every
// chunk32 within the EPS_S window. flatz aliases zq (own-row read-then-write).
__global__ __launch_bounds__(256) void vq_sel(const uint32* __restrict__ bm,
                                              const float* __restrict__ flatz,
                                              const float* __restrict__ cb,
                                              const float* __restrict__ enorm,
                                              float* __restrict__ zq,
                                              float* __restrict__ oidx) {
  const int lane = threadIdx.x & 63;
  const int row = blockIdx.x * 4 + (threadIdx.x >> 6);
  uint4 va = *(const uint4*)(bm + (size_t)row * 256 + lane * 4);
  uint32 v[4] = {va.x, va.y, va.z, va.w};
  uint32 m1 = 0, m2 = 0; int ch = 0;
#pragma unroll
  for (int s = 0; s < 4; ++s) {
    uint32 pv = v[s];
    m2 = umax(m2, umin(m1, pv));
    ch = (pv > m1) ? (lane * 4 + s) : ch;
    m1 = umax(m1, pv);
  }
#pragma unroll
  for (int m = 1; m < 64; m <<= 1) {
    uint32 o1 = (uint32)__shfl_xor((int)m1, m);
    uint32 o2 = (uint32)__shfl_xor((int)m2, m);
    int oc = __shfl_xor(ch, m);
    m2 = umax(umax(m2, o2), umin(m1, o1));
    ch = (o1 > m1) ? oc : ch;
    m1 = umax(m1, o1);
  }
  // all wave-uniform now
  float s1 = __uint_as_float(m1 & ~63u);
  float s2 = __uint_as_float(m2 & ~63u);
  int idx;
  if ((m1 & 32u) && (s1 - s2 > SM)) {
    idx = ch * 32 + (int)(m1 & 31u);  // provably the exact argmin
  } else {
    const float* zrow = flatz + (size_t)row * 256;
    unsigned long long key = u64min(chunk_exact(ch * 2, zrow, cb, enorm, lane),
                                    chunk_exact(ch * 2 + 1, zrow, cb, enorm, lane));
    float dbest;
    { unsigned int u = (unsigned int)(key >> 32);
      u = (u & 0x80000000u) ? (u & 0x7FFFFFFFu) : ~u;
      dbest = __uint_as_float(u); }
    float thr = (1024.f - 0.5f * dbest) - EPS_S;  // window lower bound
#pragma unroll
    for (int s = 0; s < 4; ++s) {
      bool cand = __uint_as_float(v[s] & ~63u) >= thr;
      unsigned long long mk = __ballot(cand);
      while (mk) {
        int L = __ffsll(mk) - 1;
        mk &= mk - 1;
        int c2 = L * 4 + s;
        if (c2 == ch) continue;
        key = u64min(key, chunk_exact(c2 * 2, zrow, cb, enorm, lane));
        key = u64min(key, chunk_exact(c2 * 2 + 1, zrow, cb, enorm, lane));
      }
    }
    idx = (int)(key & 0xFFFFFFFFull);
  }
  if (lane == 0) oidx[row] = (float)idx;
  float4 val = *(const float4*)(cb + (size_t)idx * 256 + lane * 4);
  *(float4*)(zq + (size_t)row * 256 + lane * 4) = val;  // exact fp32 gather
}

// ---- launch ----------------------------------------------------------------
extern "C" void kernel_launch(void* const* d_in, const int* in_sizes, int n_in,
                              void* d_out, int out_size, void* d_ws, size_t ws_size,
                              hipStream_t stream) {
  const float* z = (const float*)d_in[0];   // (16,256,32,32) fp32
  const float* cb = (const float*)d_in[1];  // (8192,256) fp32
  char* ws = (char*)d_ws;
  // ws: zb 8M@0 | eb 4M@8M | enorm 32K@12M | bm 16M@13M  (29 MB)
  ushort* zb = (ushort*)(ws);
  ushort* eb = (ushort*)(ws + (8u << 20));
  float* enorm = (float*)(ws + (12u << 20));
  uint32* bm = (uint32*)(ws + (13u << 20));
  float* zq = (float*)d_out;               // (16384,256) fp32
  float* oidx = zq + (size_t)NROWS * DIM;  // (16384,) as fp32 values
  float* flatz = zq;  // NHWC fp32 z lives in zq until vq_sel overwrites per-row

  prep<<<4096 + NCODES / 4, 256, 0, stream>>>(z, cb, flatz, zb, eb, enorm);
  vq_gemm<<<dim3(NCODES / 128, NROWS / 256), 256, 0, stream>>>(eb, zb, enorm, bm);
  vq_sel<<<NROWS / 4, 256, 0, stream>>>(bm, flatz, cb, enorm, zq, oidx);
}